// Round 1
// baseline (1974.201 us; speedup 1.0000x reference)
//
#include <hip/hip_runtime.h>

#define HH 128
#define NB 4
#define NVOX (NB * HH * HH * HH)   // 8,388,608 voxels per image

// Reflect index for pad=1 (jnp.pad mode='reflect'): -1 -> 1, 128 -> 126.
__device__ __forceinline__ int refl_m(int i) { return (i == 0) ? 1 : i - 1; }
__device__ __forceinline__ int refl_p(int i) { return (i == 127) ? 126 : i + 1; }

// Magnitude of the 9-filter Sobel response at flat voxel idx (b,h,w,d packed).
// Filters factor over axes (a=H, b=W, c=D) with ops s=(1,2,1), d=(-1,0,1), u=(1,1,1):
//   Sx=Gssd Sy=Gsds Sz=Gdss
//   Sd11=Gsud-Gsdu  Sd12=Gsud+Gsdu
//   Sd21=Gdus-Guds  Sd22=Gdus+Guds
//   Sd31=Gusd-Gdsu  Sd32=Gusd+Gdsu
__device__ __forceinline__ float mag_at(const float* __restrict__ img, int idx) {
    int d = idx & 127;
    int w = (idx >> 7) & 127;
    int h = (idx >> 14) & 127;
    int b = idx >> 21;

    int dm = refl_m(d), dp = refl_p(d);
    int hs0 = refl_m(h), hs2 = refl_p(h);
    int ws0 = refl_m(w), ws2 = refl_p(w);

    const float* base = img + ((size_t)b << 21);
    int hrow[3] = {hs0, h, hs2};
    int wrow[3] = {ws0, w, ws2};

    float sbD[3], ubD[3], dbS[3], sbS[3], ubS[3], dbU[3], sbU[3];
#pragma unroll
    for (int ia = 0; ia < 3; ++ia) {
        float Sc[3], Dc[3], Uc[3];
#pragma unroll
        for (int jb = 0; jb < 3; ++jb) {
            const float* row = base + ((((size_t)(hrow[ia] << 7) + wrow[jb])) << 7);
            float q0 = row[dm];
            float q1 = row[d];
            float q2 = row[dp];
            Sc[jb] = fmaf(2.0f, q1, q0 + q2);
            Dc[jb] = q2 - q0;
            Uc[jb] = (q0 + q2) + q1;
        }
        sbD[ia] = fmaf(2.0f, Dc[1], Dc[0] + Dc[2]);
        ubD[ia] = (Dc[0] + Dc[2]) + Dc[1];
        dbS[ia] = Sc[2] - Sc[0];
        sbS[ia] = fmaf(2.0f, Sc[1], Sc[0] + Sc[2]);
        ubS[ia] = (Sc[0] + Sc[2]) + Sc[1];
        dbU[ia] = Uc[2] - Uc[0];
        sbU[ia] = fmaf(2.0f, Uc[1], Uc[0] + Uc[2]);
    }

    float Gssd = fmaf(2.0f, sbD[1], sbD[0] + sbD[2]);
    float Gsud = fmaf(2.0f, ubD[1], ubD[0] + ubD[2]);
    float Gusd = (sbD[0] + sbD[2]) + sbD[1];
    float Gsds = fmaf(2.0f, dbS[1], dbS[0] + dbS[2]);
    float Guds = (dbS[0] + dbS[2]) + dbS[1];
    float Gdss = sbS[2] - sbS[0];
    float Gdus = ubS[2] - ubS[0];
    float Gsdu = fmaf(2.0f, dbU[1], dbU[0] + dbU[2]);
    float Gdsu = sbU[2] - sbU[0];

    float f0 = Gssd;
    float f1 = Gsds;
    float f2 = Gdss;
    float f3 = Gsud - Gsdu;
    float f4 = Gsud + Gsdu;
    float f5 = Gdus - Guds;
    float f6 = Gdus + Guds;
    float f7 = Gusd - Gdsu;
    float f8 = Gusd + Gdsu;

    const float e = 1e-6f;
    float s = 9.0f * 1e-6f;
    float t;
    t = f0 + e; s = fmaf(t, t, s);
    t = f1 + e; s = fmaf(t, t, s);
    t = f2 + e; s = fmaf(t, t, s);
    t = f3 + e; s = fmaf(t, t, s);
    t = f4 + e; s = fmaf(t, t, s);
    t = f5 + e; s = fmaf(t, t, s);
    t = f6 + e; s = fmaf(t, t, s);
    t = f7 + e; s = fmaf(t, t, s);
    t = f8 + e; s = fmaf(t, t, s);
    return sqrtf(s);
}

__global__ void init_ws_kernel(unsigned int* mm, double* sum) {
    if (threadIdx.x == 0) {
        mm[0] = 0xFFFFFFFFu;  // min x (uint bit pattern, mag >= 0)
        mm[1] = 0u;           // max x
        mm[2] = 0xFFFFFFFFu;  // min y
        mm[3] = 0u;           // max y
        *sum = 0.0;
    }
}

// Phase 1: compute mag for both images, track global min/max per image.
__global__ __launch_bounds__(256) void pass1_kernel(
    const float* __restrict__ x, const float* __restrict__ y,
    float* __restrict__ magx, float* __restrict__ magy,
    unsigned int* __restrict__ mm, int storeMag) {
    int gid = blockIdx.x * 256 + threadIdx.x;           // 0 .. 2*NVOX-1
    int img = (gid >= NVOX) ? 1 : 0;                    // NVOX % 256 == 0: no straddle
    int idx = gid - img * NVOX;

    const float* src = img ? y : x;
    float m = mag_at(src, idx);
    if (storeMag) {
        (img ? magy : magx)[idx] = m;
    }

    // block min/max reduce (as uint; valid since m > 0)
    unsigned int mn = __float_as_uint(m);
    unsigned int mx = mn;
#pragma unroll
    for (int off = 32; off > 0; off >>= 1) {
        unsigned int a = __shfl_down(mn, off, 64);
        unsigned int b = __shfl_down(mx, off, 64);
        mn = (a < mn) ? a : mn;
        mx = (b > mx) ? b : mx;
    }
    __shared__ unsigned int smn[4], smx[4];
    int lane = threadIdx.x & 63;
    int wid = threadIdx.x >> 6;
    if (lane == 0) { smn[wid] = mn; smx[wid] = mx; }
    __syncthreads();
    if (threadIdx.x == 0) {
        unsigned int m0 = smn[0] < smn[1] ? smn[0] : smn[1];
        unsigned int m1 = smn[2] < smn[3] ? smn[2] : smn[3];
        mn = m0 < m1 ? m0 : m1;
        unsigned int x0 = smx[0] > smx[1] ? smx[0] : smx[1];
        unsigned int x1 = smx[2] > smx[3] ? smx[2] : smx[3];
        mx = x0 > x1 ? x0 : x1;
        atomicMin(&mm[img * 2 + 0], mn);
        atomicMax(&mm[img * 2 + 1], mx);
    }
}

// Phase 2: normalize both mags, accumulate sum |nx - ny|.
__global__ __launch_bounds__(256) void pass2_kernel(
    const float* __restrict__ magx, const float* __restrict__ magy,
    const float* __restrict__ x, const float* __restrict__ y,
    const unsigned int* __restrict__ mm, double* __restrict__ sum, int loadMag) {
    int idx = blockIdx.x * 256 + threadIdx.x;  // 0 .. NVOX-1

    float vx = loadMag ? magx[idx] : mag_at(x, idx);
    float vy = loadMag ? magy[idx] : mag_at(y, idx);

    float mnx = __uint_as_float(mm[0]);
    float mxx = __uint_as_float(mm[1]);
    float mny = __uint_as_float(mm[2]);
    float mxy = __uint_as_float(mm[3]);

    float nx = (vx - mnx) / (mxx - mnx + 1e-6f);
    float ny = (vy - mny) / (mxy - mny + 1e-6f);
    float v = fabsf(nx - ny);

#pragma unroll
    for (int off = 32; off > 0; off >>= 1) v += __shfl_down(v, off, 64);
    __shared__ float sv[4];
    int lane = threadIdx.x & 63;
    int wid = threadIdx.x >> 6;
    if (lane == 0) sv[wid] = v;
    __syncthreads();
    if (threadIdx.x == 0) {
        double t = (double)sv[0] + (double)sv[1] + (double)sv[2] + (double)sv[3];
        atomicAdd(sum, t);
    }
}

__global__ void finalize_kernel(const double* __restrict__ sum, float* __restrict__ out) {
    if (threadIdx.x == 0) {
        out[0] = 1e-6f + (float)(sum[0] * (1.0 / (double)NVOX));
    }
}

extern "C" void kernel_launch(void* const* d_in, const int* in_sizes, int n_in,
                              void* d_out, int out_size, void* d_ws, size_t ws_size,
                              hipStream_t stream) {
    const float* x = (const float*)d_in[0];
    const float* y = (const float*)d_in[1];
    // d_in[2] = kernels — weights are hardcoded via the separable factorization.
    float* out = (float*)d_out;

    unsigned char* ws = (unsigned char*)d_ws;
    unsigned int* mm = (unsigned int*)ws;          // 4 uints
    double* sum = (double*)(ws + 16);              // 8-byte aligned
    float* magx = (float*)(ws + 32);
    float* magy = magx + NVOX;

    size_t need = 32 + 2 * (size_t)NVOX * sizeof(float);
    int store = (ws_size >= need) ? 1 : 0;

    init_ws_kernel<<<1, 64, 0, stream>>>(mm, sum);
    pass1_kernel<<<(2 * NVOX) / 256, 256, 0, stream>>>(x, y, magx, magy, mm, store);
    pass2_kernel<<<NVOX / 256, 256, 0, stream>>>(magx, magy, x, y, mm, sum, store);
    finalize_kernel<<<1, 64, 0, stream>>>(sum, out);
}

// Round 2
// 166.324 us; speedup vs baseline: 11.8696x; 11.8696x over previous
//
#include <hip/hip_runtime.h>

#define HH 128
#define NB 4
#define NVOX (NB * HH * HH * HH)   // 8,388,608 voxels per image

// pass1 tiling: output tile 8(h) x 4(w) x 64(d) per 256-thread block
#define TD 64
#define TW 4
#define TH 8
#define LH (TH + 2)                // 10
#define LW (TW + 2)                // 6
#define LD (TD + 2)                // 66
#define LDS_N (LH * LW * LD)       // 3960 floats = 15840 B
#define NTILE 4096                 // tiles per image: 2(d) * 32(w) * 16(h) * 4(b)
#define NBLK1 (2 * NTILE)          // 8192
#define NSLOT 64                   // contention-spreading slots

// Small scratch in module globals (NOT d_ws) so magx/magy fit exactly in ws.
// Re-initialized by init_kernel on every launch -> same work every call.
__device__ unsigned int g_mm[4 * NSLOT];   // [minx|maxx|miny|maxy] x 64 slots (uint bit pattern)
__device__ float        g_minmax[4];       // mnx, mxx, mny, mxy
__device__ double       g_psum[NSLOT];

__global__ void init_kernel() {
    int tid = threadIdx.x;
    if (tid < 4 * NSLOT) {
        // categories: 0=minx 1=maxx 2=miny 3=maxy ; min -> all-ones (float +inf-ish pattern), max -> 0
        g_mm[tid] = ((tid >> 6) & 1) ? 0u : 0xFFFFFFFFu;
    }
    if (tid < NSLOT) g_psum[tid] = 0.0;
}

// ---------------------------------------------------------------------------
// Pass 1: LDS-tiled separable Sobel magnitude + per-block min/max.
// Separable ops along each axis: s=(1,2,1), d=(-1,0,1), u=(1,1,1).
//   Sx=Gssd Sy=Gsds Sz=Gdss ; Sd11=Gsud-Gsdu Sd12=Gsud+Gsdu
//   Sd21=Gdus-Guds Sd22=Gdus+Guds ; Sd31=Gusd-Gdsu Sd32=Gusd+Gdsu
// ---------------------------------------------------------------------------
__global__ __launch_bounds__(256) void pass1_kernel(
    const float* __restrict__ x, const float* __restrict__ y,
    float* __restrict__ magx, float* __restrict__ magy) {
    __shared__ float ts[LDS_N];

    int bid = blockIdx.x;
    int img = bid >> 12;               // first 4096 blocks: x, next 4096: y
    int t   = bid & (NTILE - 1);
    int dT = t & 1;
    int wT = (t >> 1) & 31;
    int hT = (t >> 6) & 15;
    int b  = t >> 10;
    int d0 = dT * TD, w0 = wT * TW, h0 = hT * TH;

    const float* __restrict__ src = img ? y : x;
    float* __restrict__ dst = img ? magy : magx;
    int tid = threadIdx.x;

    // Stage halo tile (reflect pad=1: -1 -> 1, 128 -> 126)
    for (int e = tid; e < LDS_N; e += 256) {
        int rh  = e / (LW * LD);
        int rem = e - rh * (LW * LD);
        int rw  = rem / LD;
        int ld  = rem - rw * LD;
        int gh = h0 + rh - 1; gh = (gh < 0) ? 1 : ((gh > 127) ? 126 : gh);
        int gw = w0 + rw - 1; gw = (gw < 0) ? 1 : ((gw > 127) ? 126 : gw);
        int gd = d0 + ld - 1; gd = (gd < 0) ? 1 : ((gd > 127) ? 126 : gd);
        ts[e] = src[(((b * 128 + gh) * 128 + gw) * 128) + gd];
    }
    __syncthreads();

    int td = tid & 63;
    int tw = tid >> 6;

    // Sliding-window over h: ring of 7 b-stage values x 3 slices
    float sbD[3], ubD[3], dbS[3], sbS[3], ubS[3], dbU[3], sbU[3];
    float mn = 3.4e38f, mx = 0.0f;
    int outBase = (((b * 128 + h0) * 128 + (w0 + tw)) * 128) + (d0 + td);

#pragma unroll
    for (int a = 0; a < LH; ++a) {
        int slot = a % 3;
        const float* p = &ts[(a * LW + tw) * LD + td];
        float q00 = p[0],        q01 = p[1],          q02 = p[2];
        float q10 = p[LD],       q11 = p[LD + 1],     q12 = p[LD + 2];
        float q20 = p[2 * LD],   q21 = p[2 * LD + 1], q22 = p[2 * LD + 2];

        float S0 = fmaf(2.0f, q01, q00 + q02), D0 = q02 - q00, U0 = (q00 + q02) + q01;
        float S1 = fmaf(2.0f, q11, q10 + q12), D1 = q12 - q10, U1 = (q10 + q12) + q11;
        float S2 = fmaf(2.0f, q21, q20 + q22), D2 = q22 - q20, U2 = (q20 + q22) + q21;

        float tD = D0 + D2;
        sbD[slot] = fmaf(2.0f, D1, tD);
        ubD[slot] = tD + D1;
        float tS = S0 + S2;
        sbS[slot] = fmaf(2.0f, S1, tS);
        ubS[slot] = tS + S1;
        dbS[slot] = S2 - S0;
        float tU = U0 + U2;
        sbU[slot] = fmaf(2.0f, U1, tU);
        dbU[slot] = U2 - U0;

        if (a >= 2) {
            int s0 = (a - 2) % 3, s1 = (a - 1) % 3, s2 = slot;

            float tsbD = sbD[s0] + sbD[s2];
            float Gssd = fmaf(2.0f, sbD[s1], tsbD);
            float Gusd = tsbD + sbD[s1];
            float tubD = ubD[s0] + ubD[s2];
            float Gsud = fmaf(2.0f, ubD[s1], tubD);
            float tdbS = dbS[s0] + dbS[s2];
            float Gsds = fmaf(2.0f, dbS[s1], tdbS);
            float Guds = tdbS + dbS[s1];
            float Gdss = sbS[s2] - sbS[s0];
            float Gdus = ubS[s2] - ubS[s0];
            float tdbU = dbU[s0] + dbU[s2];
            float Gsdu = fmaf(2.0f, dbU[s1], tdbU);
            float Gdsu = sbU[s2] - sbU[s0];

            float f0 = Gssd;
            float f1 = Gsds;
            float f2 = Gdss;
            float f3 = Gsud - Gsdu;
            float f4 = Gsud + Gsdu;
            float f5 = Gdus - Guds;
            float f6 = Gdus + Guds;
            float f7 = Gusd - Gdsu;
            float f8 = Gusd + Gdsu;

            const float e1 = 1e-6f;
            float s = 9.0f * 1e-6f;
            float u;
            u = f0 + e1; s = fmaf(u, u, s);
            u = f1 + e1; s = fmaf(u, u, s);
            u = f2 + e1; s = fmaf(u, u, s);
            u = f3 + e1; s = fmaf(u, u, s);
            u = f4 + e1; s = fmaf(u, u, s);
            u = f5 + e1; s = fmaf(u, u, s);
            u = f6 + e1; s = fmaf(u, u, s);
            u = f7 + e1; s = fmaf(u, u, s);
            u = f8 + e1; s = fmaf(u, u, s);
            float m = sqrtf(s);

            dst[outBase + (a - 2) * (128 * 128)] = m;
            mn = fminf(mn, m);
            mx = fmaxf(mx, m);
        }
    }

    // Block min/max reduce (uint trick valid: m > 0)
    unsigned int umn = __float_as_uint(mn);
    unsigned int umx = __float_as_uint(mx);
#pragma unroll
    for (int off = 32; off > 0; off >>= 1) {
        unsigned int a1 = __shfl_down(umn, off, 64);
        unsigned int b1 = __shfl_down(umx, off, 64);
        umn = (a1 < umn) ? a1 : umn;
        umx = (b1 > umx) ? b1 : umx;
    }
    __shared__ unsigned int smn[4], smx[4];
    int lane = tid & 63, wid = tid >> 6;
    if (lane == 0) { smn[wid] = umn; smx[wid] = umx; }
    __syncthreads();
    if (tid == 0) {
        unsigned int m0 = smn[0] < smn[1] ? smn[0] : smn[1];
        unsigned int m1 = smn[2] < smn[3] ? smn[2] : smn[3];
        umn = m0 < m1 ? m0 : m1;
        unsigned int x0 = smx[0] > smx[1] ? smx[0] : smx[1];
        unsigned int x1 = smx[2] > smx[3] ? smx[2] : smx[3];
        umx = x0 > x1 ? x0 : x1;
        int slot = bid & (NSLOT - 1);
        atomicMin(&g_mm[(img * 2 + 0) * NSLOT + slot], umn);
        atomicMax(&g_mm[(img * 2 + 1) * NSLOT + slot], umx);
    }
}

// Reduce 64 slots per category -> g_minmax[4]. Single wave.
__global__ void reduce_mm_kernel() {
    int lane = threadIdx.x;
#pragma unroll
    for (int c = 0; c < 4; ++c) {
        unsigned int v = g_mm[c * NSLOT + lane];
        bool isMax = c & 1;
#pragma unroll
        for (int off = 32; off > 0; off >>= 1) {
            unsigned int o = __shfl_down(v, off, 64);
            v = isMax ? (o > v ? o : v) : (o < v ? o : v);
        }
        if (lane == 0) g_minmax[c] = __uint_as_float(v);
    }
}

// Pass 2: normalize both mags, partial-sum |nx - ny| into 64 double slots.
__global__ __launch_bounds__(256) void pass2_kernel(
    const float4* __restrict__ magx4, const float4* __restrict__ magy4) {
    int tid = threadIdx.x;
    float mnx = g_minmax[0], mxx = g_minmax[1];
    float mny = g_minmax[2], mxy = g_minmax[3];
    float ix = 1.0f / (mxx - mnx + 1e-6f);
    float iy = 1.0f / (mxy - mny + 1e-6f);

    float s = 0.0f;
    int base = blockIdx.x * 512 + tid;   // float4 index; 2 chunks of 256
#pragma unroll
    for (int k = 0; k < 2; ++k) {
        float4 a = magx4[base + k * 256];
        float4 b = magy4[base + k * 256];
        s += fabsf((a.x - mnx) * ix - (b.x - mny) * iy);
        s += fabsf((a.y - mnx) * ix - (b.y - mny) * iy);
        s += fabsf((a.z - mnx) * ix - (b.z - mny) * iy);
        s += fabsf((a.w - mnx) * ix - (b.w - mny) * iy);
    }
#pragma unroll
    for (int off = 32; off > 0; off >>= 1) s += __shfl_down(s, off, 64);
    __shared__ float sv[4];
    int lane = tid & 63, wid = tid >> 6;
    if (lane == 0) sv[wid] = s;
    __syncthreads();
    if (tid == 0) {
        double t = (double)sv[0] + (double)sv[1] + (double)sv[2] + (double)sv[3];
        atomicAdd(&g_psum[blockIdx.x & (NSLOT - 1)], t);
    }
}

__global__ void finalize_kernel(float* __restrict__ out) {
    int lane = threadIdx.x;
    double v = g_psum[lane];
#pragma unroll
    for (int off = 32; off > 0; off >>= 1) v += __shfl_down(v, off, 64);
    if (lane == 0) out[0] = 1e-6f + (float)(v * (1.0 / (double)NVOX));
}

extern "C" void kernel_launch(void* const* d_in, const int* in_sizes, int n_in,
                              void* d_out, int out_size, void* d_ws, size_t ws_size,
                              hipStream_t stream) {
    const float* x = (const float*)d_in[0];
    const float* y = (const float*)d_in[1];
    // d_in[2] = kernels (weights hardcoded via separable factorization)
    float* out = (float*)d_out;

    float* magx = (float*)d_ws;              // NVOX floats
    float* magy = magx + NVOX;               // NVOX floats (total 64 MiB, fits ws)

    init_kernel<<<1, 256, 0, stream>>>();
    pass1_kernel<<<NBLK1, 256, 0, stream>>>(x, y, magx, magy);
    reduce_mm_kernel<<<1, 64, 0, stream>>>();
    pass2_kernel<<<NVOX / (256 * 8), 256, 0, stream>>>((const float4*)magx, (const float4*)magy);
    finalize_kernel<<<1, 64, 0, stream>>>(out);
}

// Round 3
// 162.138 us; speedup vs baseline: 12.1761x; 1.0258x over previous
//
#include <hip/hip_runtime.h>
#include <hip/hip_fp16.h>

#define HH 128
#define NB 4
#define NVOX (NB * HH * HH * HH)   // 8,388,608 voxels per image

// pass1 tiling: output tile 8(h) x 4(w) x 64(d) per 256-thread block
#define TD 64
#define TW 4
#define TH 8
#define LH (TH + 2)                // 10
#define LW (TW + 2)                // 6
#define LD (TD + 2)                // 66
#define LDS_N (LH * LW * LD)       // 3960 floats = 15840 B
#define NTILE 4096                 // tiles per image: 2(d) * 32(w) * 16(h) * 4(b)
#define NBLK1 (2 * NTILE)          // 8192
#define P2_BLOCKS 1024

// Per-block result slots (plain stores, unique per block -> no init, no atomics).
__device__ unsigned int g_bmin[NBLK1];
__device__ unsigned int g_bmax[NBLK1];
__device__ float        g_minmax[4];       // mnx, mxx, mny, mxy
__device__ float        g_psum[P2_BLOCKS];

// ---------------------------------------------------------------------------
// Pass 1: LDS-tiled separable Sobel magnitude + per-block min/max.
// Separable ops along each axis: s=(1,2,1), d=(-1,0,1), u=(1,1,1).
//   Sx=Gssd Sy=Gsds Sz=Gdss ; Sd11=Gsud-Gsdu Sd12=Gsud+Gsdu
//   Sd21=Gdus-Guds Sd22=Gdus+Guds ; Sd31=Gusd-Gdsu Sd32=Gusd+Gdsu
// mag stored as fp16 (rounded value also used for min/max -> self-consistent).
// ---------------------------------------------------------------------------
__global__ __launch_bounds__(256) void pass1_kernel(
    const float* __restrict__ x, const float* __restrict__ y,
    __half* __restrict__ magx, __half* __restrict__ magy) {
    __shared__ float ts[LDS_N];

    int bid = blockIdx.x;
    int img = bid >> 12;               // first 4096 blocks: x, next 4096: y
    int t   = bid & (NTILE - 1);
    int dT = t & 1;
    int wT = (t >> 1) & 31;
    int hT = (t >> 6) & 15;
    int b  = t >> 10;
    int d0 = dT * TD, w0 = wT * TW, h0 = hT * TH;

    const float* __restrict__ src = img ? y : x;
    __half* __restrict__ dst = img ? magy : magx;
    int tid = threadIdx.x;

    // Stage halo tile (reflect pad=1: -1 -> 1, 128 -> 126)
    for (int e = tid; e < LDS_N; e += 256) {
        int rh  = e / (LW * LD);
        int rem = e - rh * (LW * LD);
        int rw  = rem / LD;
        int ld  = rem - rw * LD;
        int gh = h0 + rh - 1; gh = (gh < 0) ? 1 : ((gh > 127) ? 126 : gh);
        int gw = w0 + rw - 1; gw = (gw < 0) ? 1 : ((gw > 127) ? 126 : gw);
        int gd = d0 + ld - 1; gd = (gd < 0) ? 1 : ((gd > 127) ? 126 : gd);
        ts[e] = src[(((b * 128 + gh) * 128 + gw) * 128) + gd];
    }
    __syncthreads();

    int td = tid & 63;
    int tw = tid >> 6;

    // Sliding-window over h: ring of 7 b-stage values x 3 slices
    float sbD[3], ubD[3], dbS[3], sbS[3], ubS[3], dbU[3], sbU[3];
    float mn = 3.4e38f, mx = 0.0f;
    int outBase = (((b * 128 + h0) * 128 + (w0 + tw)) * 128) + (d0 + td);

#pragma unroll
    for (int a = 0; a < LH; ++a) {
        int slot = a % 3;
        const float* p = &ts[(a * LW + tw) * LD + td];
        float q00 = p[0],        q01 = p[1],          q02 = p[2];
        float q10 = p[LD],       q11 = p[LD + 1],     q12 = p[LD + 2];
        float q20 = p[2 * LD],   q21 = p[2 * LD + 1], q22 = p[2 * LD + 2];

        float a0 = q00 + q02, a1 = q10 + q12, a2 = q20 + q22;
        float S0 = fmaf(2.0f, q01, a0), D0 = q02 - q00, U0 = a0 + q01;
        float S1 = fmaf(2.0f, q11, a1), D1 = q12 - q10, U1 = a1 + q11;
        float S2 = fmaf(2.0f, q21, a2), D2 = q22 - q20, U2 = a2 + q21;

        float tD = D0 + D2;
        sbD[slot] = fmaf(2.0f, D1, tD);
        ubD[slot] = tD + D1;
        float tS = S0 + S2;
        sbS[slot] = fmaf(2.0f, S1, tS);
        ubS[slot] = tS + S1;
        dbS[slot] = S2 - S0;
        float tU = U0 + U2;
        sbU[slot] = fmaf(2.0f, U1, tU);
        dbU[slot] = U2 - U0;

        if (a >= 2) {
            int s0 = (a - 2) % 3, s1 = (a - 1) % 3, s2 = slot;

            float tsbD = sbD[s0] + sbD[s2];
            float Gssd = fmaf(2.0f, sbD[s1], tsbD);
            float Gusd = tsbD + sbD[s1];
            float tubD = ubD[s0] + ubD[s2];
            float Gsud = fmaf(2.0f, ubD[s1], tubD);
            float tdbS = dbS[s0] + dbS[s2];
            float Gsds = fmaf(2.0f, dbS[s1], tdbS);
            float Guds = tdbS + dbS[s1];
            float Gdss = sbS[s2] - sbS[s0];
            float Gdus = ubS[s2] - ubS[s0];
            float tdbU = dbU[s0] + dbU[s2];
            float Gsdu = fmaf(2.0f, dbU[s1], tdbU);
            float Gdsu = sbU[s2] - sbU[s0];

            float f0 = Gssd;
            float f1 = Gsds;
            float f2 = Gdss;
            float f3 = Gsud - Gsdu;
            float f4 = Gsud + Gsdu;
            float f5 = Gdus - Guds;
            float f6 = Gdus + Guds;
            float f7 = Gusd - Gdsu;
            float f8 = Gusd + Gdsu;

            const float e1 = 1e-6f;
            float s = 9.0f * 1e-6f;
            float u;
            u = f0 + e1; s = fmaf(u, u, s);
            u = f1 + e1; s = fmaf(u, u, s);
            u = f2 + e1; s = fmaf(u, u, s);
            u = f3 + e1; s = fmaf(u, u, s);
            u = f4 + e1; s = fmaf(u, u, s);
            u = f5 + e1; s = fmaf(u, u, s);
            u = f6 + e1; s = fmaf(u, u, s);
            u = f7 + e1; s = fmaf(u, u, s);
            u = f8 + e1; s = fmaf(u, u, s);
            float m = sqrtf(s);

            __half hm = __float2half_rn(m);
            float m2 = __half2float(hm);
            __builtin_nontemporal_store(__half_as_ushort(hm),
                (unsigned short*)&dst[outBase + (a - 2) * (128 * 128)]);
            mn = fminf(mn, m2);
            mx = fmaxf(mx, m2);
        }
    }

    // Block min/max reduce (uint trick valid: m > 0), plain store to unique slot
    unsigned int umn = __float_as_uint(mn);
    unsigned int umx = __float_as_uint(mx);
#pragma unroll
    for (int off = 32; off > 0; off >>= 1) {
        unsigned int a1 = __shfl_down(umn, off, 64);
        unsigned int b1 = __shfl_down(umx, off, 64);
        umn = (a1 < umn) ? a1 : umn;
        umx = (b1 > umx) ? b1 : umx;
    }
    __shared__ unsigned int smn[4], smx[4];
    int lane = tid & 63, wid = tid >> 6;
    if (lane == 0) { smn[wid] = umn; smx[wid] = umx; }
    __syncthreads();
    if (tid == 0) {
        unsigned int m0 = smn[0] < smn[1] ? smn[0] : smn[1];
        unsigned int m1 = smn[2] < smn[3] ? smn[2] : smn[3];
        umn = m0 < m1 ? m0 : m1;
        unsigned int x0 = smx[0] > smx[1] ? smx[0] : smx[1];
        unsigned int x1 = smx[2] > smx[3] ? smx[2] : smx[3];
        umx = x0 > x1 ? x0 : x1;
        g_bmin[bid] = umn;
        g_bmax[bid] = umx;
    }
}

// Reduce 4096 per-block slots per image -> g_minmax[4]. Single block.
__global__ __launch_bounds__(256) void reduce_mm_kernel() {
    int tid = threadIdx.x;
    __shared__ unsigned int smn[4], smx[4];
#pragma unroll
    for (int img = 0; img < 2; ++img) {
        unsigned int umn = 0xFFFFFFFFu, umx = 0u;
        for (int i = tid; i < NTILE; i += 256) {
            unsigned int a = g_bmin[img * NTILE + i];
            unsigned int b = g_bmax[img * NTILE + i];
            umn = (a < umn) ? a : umn;
            umx = (b > umx) ? b : umx;
        }
#pragma unroll
        for (int off = 32; off > 0; off >>= 1) {
            unsigned int a = __shfl_down(umn, off, 64);
            unsigned int b = __shfl_down(umx, off, 64);
            umn = (a < umn) ? a : umn;
            umx = (b > umx) ? b : umx;
        }
        int lane = tid & 63, wid = tid >> 6;
        if (lane == 0) { smn[wid] = umn; smx[wid] = umx; }
        __syncthreads();
        if (tid == 0) {
            unsigned int m0 = smn[0] < smn[1] ? smn[0] : smn[1];
            unsigned int m1 = smn[2] < smn[3] ? smn[2] : smn[3];
            unsigned int x0 = smx[0] > smx[1] ? smx[0] : smx[1];
            unsigned int x1 = smx[2] > smx[3] ? smx[2] : smx[3];
            g_minmax[img * 2 + 0] = __uint_as_float(m0 < m1 ? m0 : m1);
            g_minmax[img * 2 + 1] = __uint_as_float(x0 > x1 ? x0 : x1);
        }
        __syncthreads();
    }
}

// Pass 2: normalize both mags (fp16), partial-sum |nx-ny| into unique slots.
union U4H8 { uint4 u; __half2 h[4]; };

__global__ __launch_bounds__(256) void pass2_kernel(
    const uint4* __restrict__ magx8, const uint4* __restrict__ magy8) {
    int tid = threadIdx.x;
    float mnx = g_minmax[0], mxx = g_minmax[1];
    float mny = g_minmax[2], mxy = g_minmax[3];
    float ix = 1.0f / (mxx - mnx + 1e-6f);
    float iy = 1.0f / (mxy - mny + 1e-6f);
    float cx = -mnx * ix;
    float cy = -mny * iy;

    float s = 0.0f;
    // NVOX/8 = 1,048,576 uint4 chunks per array; 1024*256 threads * 4 iters
#pragma unroll
    for (int k = 0; k < 4; ++k) {
        int i = (k * P2_BLOCKS + blockIdx.x) * 256 + tid;
        U4H8 qa, qb;
        qa.u = magx8[i];
        qb.u = magy8[i];
#pragma unroll
        for (int j = 0; j < 4; ++j) {
            float2 va = __half22float2(qa.h[j]);
            float2 vb = __half22float2(qb.h[j]);
            s += fabsf(fmaf(va.x, ix, cx) - fmaf(vb.x, iy, cy));
            s += fabsf(fmaf(va.y, ix, cx) - fmaf(vb.y, iy, cy));
        }
    }
#pragma unroll
    for (int off = 32; off > 0; off >>= 1) s += __shfl_down(s, off, 64);
    __shared__ float sv[4];
    int lane = tid & 63, wid = tid >> 6;
    if (lane == 0) sv[wid] = s;
    __syncthreads();
    if (tid == 0) {
        g_psum[blockIdx.x] = (sv[0] + sv[1]) + (sv[2] + sv[3]);
    }
}

__global__ __launch_bounds__(256) void finalize_kernel(float* __restrict__ out) {
    int tid = threadIdx.x;
    double v = 0.0;
#pragma unroll
    for (int k = 0; k < P2_BLOCKS / 256; ++k) v += (double)g_psum[k * 256 + tid];
#pragma unroll
    for (int off = 32; off > 0; off >>= 1) v += __shfl_down(v, off, 64);
    __shared__ double sv[4];
    int lane = tid & 63, wid = tid >> 6;
    if (lane == 0) sv[wid] = v;
    __syncthreads();
    if (tid == 0) {
        double t = (sv[0] + sv[1]) + (sv[2] + sv[3]);
        out[0] = 1e-6f + (float)(t * (1.0 / (double)NVOX));
    }
}

extern "C" void kernel_launch(void* const* d_in, const int* in_sizes, int n_in,
                              void* d_out, int out_size, void* d_ws, size_t ws_size,
                              hipStream_t stream) {
    const float* x = (const float*)d_in[0];
    const float* y = (const float*)d_in[1];
    // d_in[2] = kernels (weights hardcoded via separable factorization)
    float* out = (float*)d_out;

    __half* magx = (__half*)d_ws;            // NVOX halfs (16 MiB)
    __half* magy = magx + NVOX;              // NVOX halfs (16 MiB)

    pass1_kernel<<<NBLK1, 256, 0, stream>>>(x, y, magx, magy);
    reduce_mm_kernel<<<1, 256, 0, stream>>>();
    pass2_kernel<<<P2_BLOCKS, 256, 0, stream>>>((const uint4*)magx, (const uint4*)magy);
    finalize_kernel<<<1, 256, 0, stream>>>(out);
}